// Round 1
// baseline (113.875 us; speedup 1.0000x reference)
//
#include <hip/hip_runtime.h>

// w_k = 100 * x * s_k / clip(rowdot(x, s_k), 1e-8, 1e8),  rows of length 64.
// Layout: 16 lanes per row, one float4 (16B) per lane -> fully coalesced.
// Row dot product reduced across the 16-lane group with __shfl_xor (wave=64,
// xor masks 1,2,4,8 stay inside each aligned 16-lane group).

__global__ __launch_bounds__(256) void sp2wt_fused_kernel(
    const float4* __restrict__ x,
    const float4* __restrict__ s1,
    const float4* __restrict__ s2,
    const float4* __restrict__ s3,
    const float4* __restrict__ s4,
    float4* __restrict__ out,
    int total_vec)  // = N*64/4 float4 elements per tensor
{
    int i = blockIdx.x * blockDim.x + threadIdx.x;
    if (i >= total_vec) return;

    float4 xv = x[i];
    float4 a1 = s1[i];
    float4 a2 = s2[i];
    float4 a3 = s3[i];
    float4 a4 = s4[i];

    float d1 = xv.x * a1.x + xv.y * a1.y + xv.z * a1.z + xv.w * a1.w;
    float d2 = xv.x * a2.x + xv.y * a2.y + xv.z * a2.z + xv.w * a2.w;
    float d3 = xv.x * a3.x + xv.y * a3.y + xv.z * a3.z + xv.w * a3.w;
    float d4 = xv.x * a4.x + xv.y * a4.y + xv.z * a4.z + xv.w * a4.w;

    // Reduce across the 16 lanes sharing this row (lanes are consecutive).
    #pragma unroll
    for (int m = 1; m < 16; m <<= 1) {
        d1 += __shfl_xor(d1, m);
        d2 += __shfl_xor(d2, m);
        d3 += __shfl_xor(d3, m);
        d4 += __shfl_xor(d4, m);
    }

    d1 = fminf(fmaxf(d1, 1e-8f), 1e8f);
    d2 = fminf(fmaxf(d2, 1e-8f), 1e8f);
    d3 = fminf(fmaxf(d3, 1e-8f), 1e8f);
    d4 = fminf(fmaxf(d4, 1e-8f), 1e8f);

    float r1 = 100.0f / d1;
    float r2 = 100.0f / d2;
    float r3 = 100.0f / d3;
    float r4 = 100.0f / d4;

    out[i] = make_float4(xv.x * a1.x * r1, xv.y * a1.y * r1,
                         xv.z * a1.z * r1, xv.w * a1.w * r1);
    out[i + (size_t)total_vec] = make_float4(xv.x * a2.x * r2, xv.y * a2.y * r2,
                                             xv.z * a2.z * r2, xv.w * a2.w * r2);
    out[i + 2 * (size_t)total_vec] = make_float4(xv.x * a3.x * r3, xv.y * a3.y * r3,
                                                 xv.z * a3.z * r3, xv.w * a3.w * r3);
    out[i + 3 * (size_t)total_vec] = make_float4(xv.x * a4.x * r4, xv.y * a4.y * r4,
                                                 xv.z * a4.z * r4, xv.w * a4.w * r4);
}

extern "C" void kernel_launch(void* const* d_in, const int* in_sizes, int n_in,
                              void* d_out, int out_size, void* d_ws, size_t ws_size,
                              hipStream_t stream) {
    const float4* x  = (const float4*)d_in[0];
    const float4* s1 = (const float4*)d_in[1];
    const float4* s2 = (const float4*)d_in[2];
    const float4* s3 = (const float4*)d_in[3];
    const float4* s4 = (const float4*)d_in[4];
    float4* out = (float4*)d_out;

    int total_vec = in_sizes[0] / 4;  // N*64/4
    int block = 256;
    int grid = (total_vec + block - 1) / block;
    sp2wt_fused_kernel<<<grid, block, 0, stream>>>(x, s1, s2, s3, s4, out, total_vec);
}

// Round 2
// 112.571 us; speedup vs baseline: 1.0116x; 1.0116x over previous
//
#include <hip/hip_runtime.h>

// w_k = 100 * x * s_k / clip(rowdot(x, s_k), 1e-8, 1e8),  rows of length 64.
// Layout: 16 lanes per row, one float4 (16B) per lane -> fully coalesced.
// Grid-stride (2048 blocks x 256 thr -> 8 chunks/thread), unroll 2 for ILP,
// non-temporal loads/stores (576 MB streamed once >> 256 MiB LLC).

typedef float f32x4 __attribute__((ext_vector_type(4)));

__global__ __launch_bounds__(256) void sp2wt_fused_kernel(
    const f32x4* __restrict__ x,
    const f32x4* __restrict__ s1,
    const f32x4* __restrict__ s2,
    const f32x4* __restrict__ s3,
    const f32x4* __restrict__ s4,
    f32x4* __restrict__ out,
    int total_vec)  // = N*64/4 float4 elements per tensor
{
    const int tid    = blockIdx.x * blockDim.x + threadIdx.x;
    const int stride = gridDim.x * blockDim.x;

    #pragma unroll 2
    for (int i = tid; i < total_vec; i += stride) {
        f32x4 xv = __builtin_nontemporal_load(x + i);
        f32x4 a1 = __builtin_nontemporal_load(s1 + i);
        f32x4 a2 = __builtin_nontemporal_load(s2 + i);
        f32x4 a3 = __builtin_nontemporal_load(s3 + i);
        f32x4 a4 = __builtin_nontemporal_load(s4 + i);

        f32x4 p1 = xv * a1;
        f32x4 p2 = xv * a2;
        f32x4 p3 = xv * a3;
        f32x4 p4 = xv * a4;

        float d1 = p1[0] + p1[1] + p1[2] + p1[3];
        float d2 = p2[0] + p2[1] + p2[2] + p2[3];
        float d3 = p3[0] + p3[1] + p3[2] + p3[3];
        float d4 = p4[0] + p4[1] + p4[2] + p4[3];

        // Reduce across the 16 lanes sharing this row (lanes consecutive;
        // xor masks 1,2,4,8 stay inside each aligned 16-lane group).
        #pragma unroll
        for (int m = 1; m < 16; m <<= 1) {
            d1 += __shfl_xor(d1, m);
            d2 += __shfl_xor(d2, m);
            d3 += __shfl_xor(d3, m);
            d4 += __shfl_xor(d4, m);
        }

        d1 = fminf(fmaxf(d1, 1e-8f), 1e8f);
        d2 = fminf(fmaxf(d2, 1e-8f), 1e8f);
        d3 = fminf(fmaxf(d3, 1e-8f), 1e8f);
        d4 = fminf(fmaxf(d4, 1e-8f), 1e8f);

        float r1 = 100.0f / d1;
        float r2 = 100.0f / d2;
        float r3 = 100.0f / d3;
        float r4 = 100.0f / d4;

        __builtin_nontemporal_store(p1 * r1, out + i);
        __builtin_nontemporal_store(p2 * r2, out + i + (size_t)total_vec);
        __builtin_nontemporal_store(p3 * r3, out + i + 2 * (size_t)total_vec);
        __builtin_nontemporal_store(p4 * r4, out + i + 3 * (size_t)total_vec);
    }
}

extern "C" void kernel_launch(void* const* d_in, const int* in_sizes, int n_in,
                              void* d_out, int out_size, void* d_ws, size_t ws_size,
                              hipStream_t stream) {
    const f32x4* x  = (const f32x4*)d_in[0];
    const f32x4* s1 = (const f32x4*)d_in[1];
    const f32x4* s2 = (const f32x4*)d_in[2];
    const f32x4* s3 = (const f32x4*)d_in[3];
    const f32x4* s4 = (const f32x4*)d_in[4];
    f32x4* out = (f32x4*)d_out;

    int total_vec = in_sizes[0] / 4;  // N*64/4 = 4,194,304
    int block = 256;
    int grid = 2048;  // 256 CU x 8 blocks; grid-stride covers the rest
    int max_grid = (total_vec + block - 1) / block;
    if (grid > max_grid) grid = max_grid;
    sp2wt_fused_kernel<<<grid, block, 0, stream>>>(x, s1, s2, s3, s4, out, total_vec);
}